// Round 2
// baseline (70295.374 us; speedup 1.0000x reference)
//
#include <hip/hip_runtime.h>
#include <hip/hip_cooperative_groups.h>

namespace cg = cooperative_groups;

#define HH 512
#define OO 256
#define BB 64
#define SS 1024
#define TT 256
#define KK 1280   // H(ctx) + O(target) + H(h)

typedef __attribute__((ext_vector_type(8))) short bh8;
typedef __attribute__((ext_vector_type(4))) float fx4;

__device__ __forceinline__ unsigned short f2bf(float x) {
    union { float f; unsigned int u; } v; v.f = x;
    unsigned int r = v.u + 0x7fffu + ((v.u >> 16) & 1u);
    return (unsigned short)(r >> 16);
}

// Pack W_cat = [W_ih | W_hh] (j-permuted so each h-tile block owns its 4 gates)
// into MFMA B-fragment-major bf16 layout:
//   wfrag[(((ht*40 + kk)*2 + nt)*64 + lane)*8 + r]
//   col c = nt*16 + (lane&15); gate = c>>3; j = gate*512 + ht*8 + (c&7)
//   k = kk*32 + (lane>>4)*8 + r;  k<768 -> W_ih[j][k], else W_hh[j][k-768]
__global__ void prep_weights(const float* __restrict__ W_ih,
                             const float* __restrict__ W_hh,
                             unsigned short* __restrict__ wfrag) {
    int g = blockIdx.x * 256 + threadIdx.x;     // 64*40*2*64 = 327680 groups
    if (g >= 64 * 40 * 2 * 64) return;
    int lane = g & 63;
    int nt = (g >> 6) & 1;
    int kk = (g >> 7) % 40;
    int ht = (g >> 7) / 40;
    int c = nt * 16 + (lane & 15);
    int gate = c >> 3, rr = c & 7;
    int j = gate * 512 + ht * 8 + rr;
    int kbase = kk * 32 + (lane >> 4) * 8;
    unsigned short* dst = wfrag + (size_t)g * 8;
#pragma unroll
    for (int r = 0; r < 8; ++r) {
        int k = kbase + r;
        float v = (k < 768) ? W_ih[(size_t)j * 768 + k]
                            : W_hh[(size_t)j * 512 + (k - 768)];
        dst[r] = f2bf(v);
    }
}

__global__ void prep_misc(const float* __restrict__ W_fc,
                          const float* __restrict__ hidden,
                          const float* __restrict__ cell,
                          float* __restrict__ wfcT, float* __restrict__ h,
                          float* __restrict__ c, int* __restrict__ cnt) {
    const int total = 131072 + 32768 + 32768 + 64;
    for (int i = blockIdx.x * 256 + threadIdx.x; i < total; i += gridDim.x * 256) {
        if (i < 131072) {                       // wfcT[k][o] = W_fc[o][k]
            int k = i >> 8, o = i & 255;
            wfcT[i] = W_fc[o * 512 + k];
        } else if (i < 163840) {
            int t2 = i - 131072; h[t2] = hidden[t2];
        } else if (i < 196608) {
            int t2 = i - 163840; c[t2] = cell[t2];
        } else {
            cnt[i - 196608] = 0;
        }
    }
}

__global__ void __launch_bounds__(256, 4)
decoder_main(const float* __restrict__ enc, const float* __restrict__ target,
             const float* __restrict__ b_ih, const float* __restrict__ b_hh,
             const float* __restrict__ b_fc, float* __restrict__ out,
             float* __restrict__ h, float* __restrict__ c,
             const float* __restrict__ wfcT,
             const unsigned short* __restrict__ wfrag,
             unsigned short* __restrict__ xb,
             float* __restrict__ pm, float* __restrict__ pl,
             float* __restrict__ pctx, int* __restrict__ cnt) {
    cg::grid_group grid = cg::this_grid();
    const int tid = threadIdx.x;
    const int lane = tid & 63;
    const int w = tid >> 6;

    __shared__ union {
        struct { float m[4]; float l[4]; float ctx[4][512]; int flag; } a;
        struct { float g[64][32]; } b;
        struct { float acc[4][64]; } o;
    } sh;

    for (int t = 0; t <= TT; ++t) {
        // ---------------- Phase A: attention(t) + out(t-1) ----------------
        const int nA = (t < TT) ? 1024 : 0;
        const int nU = nA + ((t > 0) ? 256 : 0);
        for (int u = blockIdx.x; u < nU; u += gridDim.x) {
            if (u < nA) {
                const int b = u >> 4, ch = u & 15;
                const float4 h0 = *(const float4*)(h + b * HH + lane * 4);
                const float4 h1 = *(const float4*)(h + b * HH + 256 + lane * 4);
                float m = -3.0e38f, l = 0.f;
                float4 c0 = {0, 0, 0, 0}, c1 = {0, 0, 0, 0};
                const float* er = enc + ((size_t)(b * SS + ch * 64 + w * 16)) * HH;
                for (int r = 0; r < 16; ++r) {
                    const float4 e0 = *(const float4*)(er + lane * 4);
                    const float4 e1 = *(const float4*)(er + 256 + lane * 4);
                    float d = e0.x * h0.x + e0.y * h0.y + e0.z * h0.z + e0.w * h0.w
                            + e1.x * h1.x + e1.y * h1.y + e1.z * h1.z + e1.w * h1.w;
#pragma unroll
                    for (int off = 32; off; off >>= 1) d += __shfl_xor(d, off);
                    if (d > m) {                      // wave-uniform branch
                        float f = __expf(m - d);
                        l *= f;
                        c0.x *= f; c0.y *= f; c0.z *= f; c0.w *= f;
                        c1.x *= f; c1.y *= f; c1.z *= f; c1.w *= f;
                        m = d;
                    }
                    float p = __expf(d - m);
                    l += p;
                    c0.x += p * e0.x; c0.y += p * e0.y; c0.z += p * e0.z; c0.w += p * e0.w;
                    c1.x += p * e1.x; c1.y += p * e1.y; c1.z += p * e1.z; c1.w += p * e1.w;
                    er += HH;
                }
                if (lane == 0) { sh.a.m[w] = m; sh.a.l[w] = l; }
                *(float4*)&sh.a.ctx[w][lane * 4] = c0;
                *(float4*)&sh.a.ctx[w][256 + lane * 4] = c1;
                __syncthreads();
                // block-level combine of the 4 wave partials
                float M = fmaxf(fmaxf(sh.a.m[0], sh.a.m[1]), fmaxf(sh.a.m[2], sh.a.m[3]));
                float wg[4]; float ls = 0.f;
#pragma unroll
                for (int q = 0; q < 4; ++q) { wg[q] = __expf(sh.a.m[q] - M); ls += wg[q] * sh.a.l[q]; }
                const int hh = tid * 2;
                float v0 = wg[0] * sh.a.ctx[0][hh] + wg[1] * sh.a.ctx[1][hh]
                         + wg[2] * sh.a.ctx[2][hh] + wg[3] * sh.a.ctx[3][hh];
                float v1 = wg[0] * sh.a.ctx[0][hh + 1] + wg[1] * sh.a.ctx[1][hh + 1]
                         + wg[2] * sh.a.ctx[2][hh + 1] + wg[3] * sh.a.ctx[3][hh + 1];
                float* pc = pctx + ((size_t)(b * 16 + ch)) * HH;
                *(float2*)(pc + hh) = make_float2(v0, v1);
                if (tid == 0) { pm[b * 16 + ch] = M; pl[b * 16 + ch] = ls; }
                __threadfence();
                __syncthreads();
                if (tid == 0) sh.a.flag = atomicAdd(&cnt[b], 1);
                __syncthreads();
                if (sh.a.flag == 15) {
                    // this block is last for b: combine 16 chunk partials -> x_bf16
                    __threadfence();
                    float Mb = -3.0e38f;
#pragma unroll
                    for (int q2 = 0; q2 < 16; ++q2) Mb = fmaxf(Mb, pm[b * 16 + q2]);
                    float wq[16]; float lsb = 0.f;
#pragma unroll
                    for (int q2 = 0; q2 < 16; ++q2) {
                        wq[q2] = __expf(pm[b * 16 + q2] - Mb);
                        lsb += wq[q2] * pl[b * 16 + q2];
                    }
                    const float inv = 1.0f / lsb;
                    const int h2 = tid * 2;
                    float s0 = 0.f, s1 = 0.f;
#pragma unroll
                    for (int q2 = 0; q2 < 16; ++q2) {
                        const float* pc2 = pctx + ((size_t)(b * 16 + q2)) * HH + h2;
                        s0 += wq[q2] * pc2[0];
                        s1 += wq[q2] * pc2[1];
                    }
                    xb[b * KK + h2]     = f2bf(s0 * inv);
                    xb[b * KK + h2 + 1] = f2bf(s1 * inv);
                    if (tid < 128) {
                        const float* tg = target + ((size_t)b * TT + t) * OO + tid * 2;
                        xb[b * KK + 512 + tid * 2]     = f2bf(tg[0]);
                        xb[b * KK + 512 + tid * 2 + 1] = f2bf(tg[1]);
                    }
                    xb[b * KK + 768 + h2]     = f2bf(h[b * HH + h2]);
                    xb[b * KK + 768 + h2 + 1] = f2bf(h[b * HH + h2 + 1]);
                    if (tid == 0) cnt[b] = 0;
                }
                __syncthreads();
            } else {
                // out(t-1): unit v -> (b, quarter of O), K split 4-ways across waves
                const int v = u - nA;
                const int b = v >> 2, oq = v & 3;
                const int ol = tid & 63, kq = tid >> 6;
                const int o = oq * 64 + ol;
                float acc = 0.f;
                const float* hp = h + b * HH + kq * 128;
                const float* wp = wfcT + (size_t)(kq * 128) * OO + o;
#pragma unroll 4
                for (int k2 = 0; k2 < 128; ++k2) acc += hp[k2] * wp[(size_t)k2 * OO];
                sh.o.acc[kq][ol] = acc;
                __syncthreads();
                if (tid < 64) {
                    float vv = sh.o.acc[0][tid] + sh.o.acc[1][tid]
                             + sh.o.acc[2][tid] + sh.o.acc[3][tid] + b_fc[oq * 64 + tid];
                    out[((size_t)b * TT + (t - 1)) * OO + oq * 64 + tid] = vv;
                }
                __syncthreads();
            }
        }
        if (t == TT) break;
        grid.sync();

        // ---------------- Phase B: gates MFMA + cell update ----------------
        for (int u = blockIdx.x; u < 64; u += gridDim.x) {
            const int ht = u;
            fx4 a0 = {0, 0, 0, 0}, a1 = {0, 0, 0, 0};
            const int bro = 16 * w + (lane & 15);
            const int kg = lane >> 4;
            const unsigned short* wf = wfrag + ((size_t)ht * 40 * 2) * 512;
            for (int kk = 0; kk < 40; ++kk) {
                bh8 av = *(const bh8*)(xb + (size_t)bro * KK + kk * 32 + kg * 8);
                bh8 b0 = *(const bh8*)(wf + (kk * 2 + 0) * 512 + lane * 8);
                bh8 b1 = *(const bh8*)(wf + (kk * 2 + 1) * 512 + lane * 8);
                a0 = __builtin_amdgcn_mfma_f32_16x16x32_bf16(av, b0, a0, 0, 0, 0);
                a1 = __builtin_amdgcn_mfma_f32_16x16x32_bf16(av, b1, a1, 0, 0, 0);
            }
            __syncthreads();
            const int crow = (lane >> 4) * 4;
#pragma unroll
            for (int r = 0; r < 4; ++r) {
                sh.b.g[16 * w + crow + r][lane & 15]        = a0[r];
                sh.b.g[16 * w + crow + r][16 + (lane & 15)] = a1[r];
            }
            __syncthreads();
#pragma unroll
            for (int p = 0; p < 2; ++p) {
                const int idx = tid * 2 + p;
                const int b = idx >> 3, r = idx & 7;
                const int hidx = ht * 8 + r;
                float gi = sh.b.g[b][r]      + b_ih[hidx]         + b_hh[hidx];
                float gf = sh.b.g[b][8 + r]  + b_ih[512 + hidx]   + b_hh[512 + hidx];
                float gg = sh.b.g[b][16 + r] + b_ih[1024 + hidx]  + b_hh[1024 + hidx];
                float go = sh.b.g[b][24 + r] + b_ih[1536 + hidx]  + b_hh[1536 + hidx];
                float ig = 1.f / (1.f + __expf(-gi));
                float fg = 1.f / (1.f + __expf(-gf));
                float g2 = tanhf(gg);
                float og = 1.f / (1.f + __expf(-go));
                float cn = fg * c[b * HH + hidx] + ig * g2;
                float hn = og * tanhf(cn);
                c[b * HH + hidx] = cn;
                h[b * HH + hidx] = hn;
            }
            __syncthreads();
        }
        grid.sync();
    }
}

extern "C" void kernel_launch(void* const* d_in, const int* in_sizes, int n_in,
                              void* d_out, int out_size, void* d_ws, size_t ws_size,
                              hipStream_t stream) {
    const float* enc    = (const float*)d_in[0];
    const float* hidden = (const float*)d_in[1];
    const float* cellp  = (const float*)d_in[2];
    const float* target = (const float*)d_in[3];
    const float* W_ih   = (const float*)d_in[4];
    const float* W_hh   = (const float*)d_in[5];
    const float* b_ih   = (const float*)d_in[6];
    const float* b_hh   = (const float*)d_in[7];
    const float* W_fc   = (const float*)d_in[8];
    const float* b_fc   = (const float*)d_in[9];
    float* out = (float*)d_out;

    char* base = (char*)d_ws;
    float* h              = (float*)(base + 0);          // 64*512 f32
    float* c              = (float*)(base + 131072);     // 64*512 f32
    float* wfcT           = (float*)(base + 262144);     // 512*256 f32
    unsigned short* wfrag = (unsigned short*)(base + 786432);   // 2.62M bf16
    unsigned short* xb    = (unsigned short*)(base + 6029312);  // 64*1280 bf16
    float* pm             = (float*)(base + 6193152);    // 64*16
    float* pl             = (float*)(base + 6197248);    // 64*16
    float* pctx           = (float*)(base + 6201344);    // 64*16*512 f32
    int* cnt              = (int*)(base + 8298496);      // 64

    hipLaunchKernelGGL(prep_weights, dim3(1280), dim3(256), 0, stream, W_ih, W_hh, wfrag);
    hipLaunchKernelGGL(prep_misc, dim3(768), dim3(256), 0, stream,
                       W_fc, hidden, cellp, wfcT, h, c, cnt);

    int grid = 1024;
    int occ = 0;
    if (hipOccupancyMaxActiveBlocksPerMultiprocessor(&occ, (const void*)decoder_main, 256, 0) == hipSuccess
        && occ > 0) {
        int g = occ * 256;   // MI355X: 256 CUs
        if (g < 1) g = 1;
        if (g < grid) grid = g;
    }

    void* args[] = { (void*)&enc, (void*)&target, (void*)&b_ih, (void*)&b_hh,
                     (void*)&b_fc, (void*)&out, (void*)&h, (void*)&c,
                     (void*)&wfcT, (void*)&wfrag, (void*)&xb,
                     (void*)&pm, (void*)&pl, (void*)&pctx, (void*)&cnt };
    hipLaunchCooperativeKernel((const void*)decoder_main, dim3(grid), dim3(256),
                               args, 0, stream);
}

// Round 4
// 38446.600 us; speedup vs baseline: 1.8284x; 1.8284x over previous
//
#include <hip/hip_runtime.h>

#define HH 512
#define OO 256
#define BB 64
#define SS 1024
#define TT 256
#define KK 1280   // H(ctx) + O(target) + H(h)

typedef __attribute__((ext_vector_type(8))) short bh8;
typedef __attribute__((ext_vector_type(4))) float fx4;

__device__ __forceinline__ unsigned short f2bf(float x) {
    union { float f; unsigned int u; } v; v.f = x;
    unsigned int r = v.u + 0x7fffu + ((v.u >> 16) & 1u);
    return (unsigned short)(r >> 16);
}

// Pack W_cat = [W_ih | W_hh] (j-permuted so each h-tile block owns its 4 gates)
// into MFMA B-fragment-major bf16 layout. See round-0 comment for indexing.
__global__ void prep_weights(const float* __restrict__ W_ih,
                             const float* __restrict__ W_hh,
                             unsigned short* __restrict__ wfrag) {
    int g = blockIdx.x * 256 + threadIdx.x;     // 64*40*2*64 = 327680 groups
    if (g >= 64 * 40 * 2 * 64) return;
    int lane = g & 63;
    int nt = (g >> 6) & 1;
    int kk = (g >> 7) % 40;
    int ht = (g >> 7) / 40;
    int c = nt * 16 + (lane & 15);
    int gate = c >> 3, rr = c & 7;
    int j = gate * 512 + ht * 8 + rr;
    int kbase = kk * 32 + (lane >> 4) * 8;
    unsigned short* dst = wfrag + (size_t)g * 8;
#pragma unroll
    for (int r = 0; r < 8; ++r) {
        int k = kbase + r;
        float v = (k < 768) ? W_ih[(size_t)j * 768 + k]
                            : W_hh[(size_t)j * 512 + (k - 768)];
        dst[r] = f2bf(v);
    }
}

__global__ void prep_misc(const float* __restrict__ W_fc,
                          const float* __restrict__ hidden,
                          const float* __restrict__ cell,
                          float* __restrict__ wfcT, float* __restrict__ h,
                          float* __restrict__ c, int* __restrict__ cnt) {
    const int total = 131072 + 32768 + 32768 + 64;
    for (int i = blockIdx.x * 256 + threadIdx.x; i < total; i += gridDim.x * 256) {
        if (i < 131072) {                       // wfcT[k][o] = W_fc[o][k]
            int k = i >> 8, o = i & 255;
            wfcT[i] = W_fc[o * 512 + k];
        } else if (i < 163840) {
            int t2 = i - 131072; h[t2] = hidden[t2];
        } else if (i < 196608) {
            int t2 = i - 163840; c[t2] = cell[t2];
        } else {
            cnt[i - 196608] = 0;
        }
    }
}

__device__ __forceinline__ void fc_unit(int v, int tprev,
                                        const float* __restrict__ h,
                                        const float* __restrict__ wfcT,
                                        const float* __restrict__ b_fc,
                                        float* __restrict__ out,
                                        float (*shacc)[64]) {
    const int tid = threadIdx.x;
    const int b = v >> 2, oq = v & 3;
    const int ol = tid & 63, kq = tid >> 6;
    const int o = oq * 64 + ol;
    float acc = 0.f;
    const float* hp = h + b * HH + kq * 128;
    const float* wp = wfcT + (size_t)(kq * 128) * OO + o;
#pragma unroll 8
    for (int k2 = 0; k2 < 128; ++k2) acc += hp[k2] * wp[(size_t)k2 * OO];
    shacc[kq][ol] = acc;
    __syncthreads();
    if (tid < 64) {
        float vv = shacc[0][tid] + shacc[1][tid]
                 + shacc[2][tid] + shacc[3][tid] + b_fc[oq * 64 + tid];
        out[((size_t)b * TT + tprev) * OO + oq * 64 + tid] = vv;
    }
}

// Blocks 0..1023: attention(t) for (b, 64-row chunk) + last-block combine -> xb.
// Blocks 1024..1279: FC producing out[t-1] (needs only h, overlaps attention).
__global__ void __launch_bounds__(256)
step_attn(int t, const float* __restrict__ enc, const float* __restrict__ target,
          const float* __restrict__ h, unsigned short* __restrict__ xb,
          float* __restrict__ pm, float* __restrict__ pl,
          float* __restrict__ pctx, int* __restrict__ cnt,
          const float* __restrict__ wfcT, const float* __restrict__ b_fc,
          float* __restrict__ out) {
    const int tid = threadIdx.x;
    const int lane = tid & 63;
    const int w = tid >> 6;

    __shared__ union {
        struct { float m[4]; float l[4]; float ctx[4][512]; int flag; } a;
        struct { float acc[4][64]; } o;
    } sh;

    const int u = blockIdx.x;
    if (u < 1024) {
        const int b = u >> 4, ch = u & 15;
        const float4 h0 = *(const float4*)(h + b * HH + lane * 4);
        const float4 h1 = *(const float4*)(h + b * HH + 256 + lane * 4);
        float m = -3.0e38f, l = 0.f;
        float4 c0 = {0, 0, 0, 0}, c1 = {0, 0, 0, 0};
        const float* er = enc + ((size_t)(b * SS + ch * 64 + w * 16)) * HH;
        // pairwise rows: two independent dot-reduces in flight per iteration
        for (int rp = 0; rp < 8; ++rp) {
            const float4 e0 = *(const float4*)(er + lane * 4);
            const float4 e1 = *(const float4*)(er + 256 + lane * 4);
            const float4 f0 = *(const float4*)(er + HH + lane * 4);
            const float4 f1 = *(const float4*)(er + HH + 256 + lane * 4);
            float dA = e0.x * h0.x + e0.y * h0.y + e0.z * h0.z + e0.w * h0.w
                     + e1.x * h1.x + e1.y * h1.y + e1.z * h1.z + e1.w * h1.w;
            float dB = f0.x * h0.x + f0.y * h0.y + f0.z * h0.z + f0.w * h0.w
                     + f1.x * h1.x + f1.y * h1.y + f1.z * h1.z + f1.w * h1.w;
#pragma unroll
            for (int off = 32; off; off >>= 1) {
                dA += __shfl_xor(dA, off);
                dB += __shfl_xor(dB, off);
            }
            const float mx = fmaxf(dA, dB);
            if (mx > m) {                      // wave-uniform branch
                const float fs = __expf(m - mx);
                l *= fs;
                c0.x *= fs; c0.y *= fs; c0.z *= fs; c0.w *= fs;
                c1.x *= fs; c1.y *= fs; c1.z *= fs; c1.w *= fs;
                m = mx;
            }
            const float pA = __expf(dA - m);
            const float pB = __expf(dB - m);
            l += pA + pB;
            c0.x += pA * e0.x + pB * f0.x; c0.y += pA * e0.y + pB * f0.y;
            c0.z += pA * e0.z + pB * f0.z; c0.w += pA * e0.w + pB * f0.w;
            c1.x += pA * e1.x + pB * f1.x; c1.y += pA * e1.y + pB * f1.y;
            c1.z += pA * e1.z + pB * f1.z; c1.w += pA * e1.w + pB * f1.w;
            er += 2 * HH;
        }
        if (lane == 0) { sh.a.m[w] = m; sh.a.l[w] = l; }
        *(float4*)&sh.a.ctx[w][lane * 4] = c0;
        *(float4*)&sh.a.ctx[w][256 + lane * 4] = c1;
        __syncthreads();
        // block-level combine of the 4 wave partials
        float M = fmaxf(fmaxf(sh.a.m[0], sh.a.m[1]), fmaxf(sh.a.m[2], sh.a.m[3]));
        float wg[4]; float ls = 0.f;
#pragma unroll
        for (int q = 0; q < 4; ++q) { wg[q] = __expf(sh.a.m[q] - M); ls += wg[q] * sh.a.l[q]; }
        const int hh = tid * 2;
        float v0 = wg[0] * sh.a.ctx[0][hh] + wg[1] * sh.a.ctx[1][hh]
                 + wg[2] * sh.a.ctx[2][hh] + wg[3] * sh.a.ctx[3][hh];
        float v1 = wg[0] * sh.a.ctx[0][hh + 1] + wg[1] * sh.a.ctx[1][hh + 1]
                 + wg[2] * sh.a.ctx[2][hh + 1] + wg[3] * sh.a.ctx[3][hh + 1];
        float* pc = pctx + ((size_t)(b * 16 + ch)) * HH;
        *(float2*)(pc + hh) = make_float2(v0, v1);
        if (tid == 0) { pm[b * 16 + ch] = M; pl[b * 16 + ch] = ls; }
        __threadfence();
        __syncthreads();
        if (tid == 0) sh.a.flag = atomicAdd(&cnt[b], 1);
        __syncthreads();
        if (sh.a.flag == 15) {
            // this block is last for b: combine 16 chunk partials -> x_bf16
            __threadfence();
            float Mb = -3.0e38f;
#pragma unroll
            for (int q2 = 0; q2 < 16; ++q2) Mb = fmaxf(Mb, pm[b * 16 + q2]);
            float wq[16]; float lsb = 0.f;
#pragma unroll
            for (int q2 = 0; q2 < 16; ++q2) {
                wq[q2] = __expf(pm[b * 16 + q2] - Mb);
                lsb += wq[q2] * pl[b * 16 + q2];
            }
            const float inv = 1.0f / lsb;
            const int h2 = tid * 2;
            float s0 = 0.f, s1 = 0.f;
#pragma unroll
            for (int q2 = 0; q2 < 16; ++q2) {
                const float* pc2 = pctx + ((size_t)(b * 16 + q2)) * HH + h2;
                s0 += wq[q2] * pc2[0];
                s1 += wq[q2] * pc2[1];
            }
            xb[b * KK + h2]     = f2bf(s0 * inv);
            xb[b * KK + h2 + 1] = f2bf(s1 * inv);
            if (tid < 128) {
                const float* tg = target + ((size_t)b * TT + t) * OO + tid * 2;
                xb[b * KK + 512 + tid * 2]     = f2bf(tg[0]);
                xb[b * KK + 512 + tid * 2 + 1] = f2bf(tg[1]);
            }
            xb[b * KK + 768 + h2]     = f2bf(h[b * HH + h2]);
            xb[b * KK + 768 + h2 + 1] = f2bf(h[b * HH + h2 + 1]);
            if (tid == 0) cnt[b] = 0;              // re-arm for next step
        }
    } else if (t > 0) {
        fc_unit(u - 1024, t - 1, h, wfcT, b_fc, out, sh.o.acc);
    }
}

// One block per h-tile (64 blocks): gates MFMA over K=1280 + cell/h update.
__global__ void __launch_bounds__(256)
step_gates(const unsigned short* __restrict__ xb,
           const unsigned short* __restrict__ wfrag,
           const float* __restrict__ b_ih, const float* __restrict__ b_hh,
           float* __restrict__ h, float* __restrict__ c) {
    const int tid = threadIdx.x;
    const int lane = tid & 63;
    const int w = tid >> 6;
    __shared__ float g[64][32];

    const int ht = blockIdx.x;
    fx4 a0 = {0, 0, 0, 0}, a1 = {0, 0, 0, 0};
    const int bro = 16 * w + (lane & 15);
    const int kg = lane >> 4;
    const unsigned short* wf = wfrag + ((size_t)ht * 40 * 2) * 512;
    for (int kk = 0; kk < 40; ++kk) {
        bh8 av = *(const bh8*)(xb + (size_t)bro * KK + kk * 32 + kg * 8);
        bh8 b0 = *(const bh8*)(wf + (kk * 2 + 0) * 512 + lane * 8);
        bh8 b1 = *(const bh8*)(wf + (kk * 2 + 1) * 512 + lane * 8);
        a0 = __builtin_amdgcn_mfma_f32_16x16x32_bf16(av, b0, a0, 0, 0, 0);
        a1 = __builtin_amdgcn_mfma_f32_16x16x32_bf16(av, b1, a1, 0, 0, 0);
    }
    const int crow = (lane >> 4) * 4;
#pragma unroll
    for (int r = 0; r < 4; ++r) {
        g[16 * w + crow + r][lane & 15]        = a0[r];
        g[16 * w + crow + r][16 + (lane & 15)] = a1[r];
    }
    __syncthreads();
#pragma unroll
    for (int p = 0; p < 2; ++p) {
        const int idx = tid * 2 + p;
        const int b = idx >> 3, r = idx & 7;
        const int hidx = ht * 8 + r;
        float gi = g[b][r]      + b_ih[hidx]        + b_hh[hidx];
        float gf = g[b][8 + r]  + b_ih[512 + hidx]  + b_hh[512 + hidx];
        float gg = g[b][16 + r] + b_ih[1024 + hidx] + b_hh[1024 + hidx];
        float go = g[b][24 + r] + b_ih[1536 + hidx] + b_hh[1536 + hidx];
        float ig = 1.f / (1.f + __expf(-gi));
        float fg = 1.f / (1.f + __expf(-gf));
        float g2 = tanhf(gg);
        float og = 1.f / (1.f + __expf(-go));
        float cn = fg * c[b * HH + hidx] + ig * g2;
        float hn = og * tanhf(cn);
        c[b * HH + hidx] = cn;
        h[b * HH + hidx] = hn;
    }
}

__global__ void __launch_bounds__(256)
fc_final(const float* __restrict__ h, const float* __restrict__ wfcT,
         const float* __restrict__ b_fc, float* __restrict__ out) {
    __shared__ float acc[4][64];
    fc_unit(blockIdx.x, TT - 1, h, wfcT, b_fc, out, acc);
}

extern "C" void kernel_launch(void* const* d_in, const int* in_sizes, int n_in,
                              void* d_out, int out_size, void* d_ws, size_t ws_size,
                              hipStream_t stream) {
    const float* enc    = (const float*)d_in[0];
    const float* hidden = (const float*)d_in[1];
    const float* cellp  = (const float*)d_in[2];
    const float* target = (const float*)d_in[3];
    const float* W_ih   = (const float*)d_in[4];
    const float* W_hh   = (const float*)d_in[5];
    const float* b_ih   = (const float*)d_in[6];
    const float* b_hh   = (const float*)d_in[7];
    const float* W_fc   = (const float*)d_in[8];
    const float* b_fc   = (const float*)d_in[9];
    float* out = (float*)d_out;

    char* base = (char*)d_ws;
    float* h              = (float*)(base + 0);          // 64*512 f32
    float* c              = (float*)(base + 131072);     // 64*512 f32
    float* wfcT           = (float*)(base + 262144);     // 512*256 f32
    unsigned short* wfrag = (unsigned short*)(base + 786432);   // 2.62M bf16
    unsigned short* xb    = (unsigned short*)(base + 6029312);  // 64*1280 bf16
    float* pm             = (float*)(base + 6193152);    // 64*16
    float* pl             = (float*)(base + 6197248);    // 64*16
    float* pctx           = (float*)(base + 6201344);    // 64*16*512 f32
    int* cnt              = (int*)(base + 8298496);      // 64

    hipLaunchKernelGGL(prep_weights, dim3(1280), dim3(256), 0, stream, W_ih, W_hh, wfrag);
    hipLaunchKernelGGL(prep_misc, dim3(768), dim3(256), 0, stream,
                       W_fc, hidden, cellp, wfcT, h, c, cnt);

    for (int t = 0; t < TT; ++t) {
        hipLaunchKernelGGL(step_attn, dim3(1280), dim3(256), 0, stream,
                           t, enc, target, h, xb, pm, pl, pctx, cnt,
                           wfcT, b_fc, out);
        hipLaunchKernelGGL(step_gates, dim3(64), dim3(256), 0, stream,
                           xb, wfrag, b_ih, b_hh, h, c);
    }
    hipLaunchKernelGGL(fc_final, dim3(256), dim3(256), 0, stream,
                       h, wfcT, b_fc, out);
}